// Round 3
// baseline (1178.107 us; speedup 1.0000x reference)
//
#include <hip/hip_runtime.h>

// RGCN 3-layer forward, MI355X — atomic-free edge aggregation via per-call CSR.
//
// Per layer l:
//   xW[n,r,:] = h @ W[l,r] (r=0..2), outh[n,:] = h @ Wsl[l] + bias[l]   (GEMM)
//   outh[n,:] += sum over incoming edges e (dst==n) of xW[src[e], et[e], :]
// CSR (edges grouped by dst) built once per call, reused for all 3 layers.

#define DD 128

// ============================ GEMM =========================================
// grid.x = ceil(N/128), grid.y = 4 (y<3: relation y -> xW; y==3: self -> outh+bias)
// block = 256 threads, each thread computes 8 rows x 8 cols.
// Row assignment is INTERLEAVED (row = i*16 + ty) so that within a wave the
// 4 ty-groups' A-reads sit 40 floats apart -> banks {0,8,16,24}: conflict-free.
__global__ __launch_bounds__(256) void rgcn_xform(
    const float* __restrict__ h,      // [N,128]
    const float* __restrict__ Wl,     // [3,128,128]
    const float* __restrict__ Wsl,    // [128,128]
    const float* __restrict__ bl,     // [128]
    float* __restrict__ xW,           // [N,3,128]
    float* __restrict__ outh,         // [N,128]
    int nNodes)
{
    constexpr int BM = 128, BK = 32;
    constexpr int AST = 40;                 // padded LDS stride (40*4B = 160B, 16B-aligned rows)
    __shared__ float As[BM][AST];
    __shared__ float Bs[BK][DD];
    const int y = blockIdx.y;
    const float* Wsrc = (y < 3) ? (Wl + (size_t)y * DD * DD) : Wsl;
    const int row0 = blockIdx.x * BM;
    const int t  = threadIdx.x;
    const int tx = t & 15;                  // col group: cols tx*8 .. tx*8+7
    const int ty = t >> 4;                  // 0..15; thread's rows are i*16+ty, i=0..7

    float4 acc[8][2];
    #pragma unroll
    for (int i = 0; i < 8; ++i) {
        acc[i][0] = float4{0.f, 0.f, 0.f, 0.f};
        acc[i][1] = float4{0.f, 0.f, 0.f, 0.f};
    }

    for (int kc = 0; kc < DD; kc += BK) {
        // ---- stage A chunk [128 rows x 32 k] ----
        #pragma unroll
        for (int i = 0; i < 4; ++i) {
            int idx = t + i * 256;          // float4 slot 0..1023
            int r = idx >> 3;               // 0..127
            int c = (idx & 7) << 2;         // 0..28
            float4 v = float4{0.f, 0.f, 0.f, 0.f};
            int gr = row0 + r;
            if (gr < nNodes)
                v = *reinterpret_cast<const float4*>(h + (size_t)gr * DD + kc + c);
            *reinterpret_cast<float4*>(&As[r][c]) = v;
        }
        // ---- stage B chunk [32 k x 128 cols] ----
        #pragma unroll
        for (int i = 0; i < 4; ++i) {
            int idx = t + i * 256;
            int kk = idx >> 5;              // 0..31
            int c  = (idx & 31) << 2;       // 0..124
            *reinterpret_cast<float4*>(&Bs[kk][c]) =
                *reinterpret_cast<const float4*>(Wsrc + (size_t)(kc + kk) * DD + c);
        }
        __syncthreads();

        #pragma unroll
        for (int k4 = 0; k4 < BK; k4 += 4) {
            float4 a[8];
            #pragma unroll
            for (int i = 0; i < 8; ++i)
                a[i] = *reinterpret_cast<const float4*>(&As[i * 16 + ty][k4]);

#define RGCN_FMA_J(J, COMP)                                                        \
            {                                                                      \
                float4 b0 = *reinterpret_cast<const float4*>(&Bs[k4 + J][tx * 8]); \
                float4 b1 = *reinterpret_cast<const float4*>(&Bs[k4 + J][tx * 8 + 4]); \
                _Pragma("unroll")                                                  \
                for (int i = 0; i < 8; ++i) {                                      \
                    const float av = a[i].COMP;                                    \
                    acc[i][0].x += av * b0.x; acc[i][0].y += av * b0.y;            \
                    acc[i][0].z += av * b0.z; acc[i][0].w += av * b0.w;            \
                    acc[i][1].x += av * b1.x; acc[i][1].y += av * b1.y;            \
                    acc[i][1].z += av * b1.z; acc[i][1].w += av * b1.w;            \
                }                                                                  \
            }
            RGCN_FMA_J(0, x)
            RGCN_FMA_J(1, y)
            RGCN_FMA_J(2, z)
            RGCN_FMA_J(3, w)
#undef RGCN_FMA_J
        }
        __syncthreads();
    }

    // ---- epilogue: thread's row i is global row0 + i*16 + ty ----
    if (y < 3) {
        #pragma unroll
        for (int i = 0; i < 8; ++i) {
            int gr = row0 + i * 16 + ty;
            if (gr < nNodes) {
                float* p = xW + ((size_t)gr * 3 + y) * DD + tx * 8;
                *reinterpret_cast<float4*>(p)     = acc[i][0];
                *reinterpret_cast<float4*>(p + 4) = acc[i][1];
            }
        }
    } else {
        float4 bb0 = *reinterpret_cast<const float4*>(bl + tx * 8);
        float4 bb1 = *reinterpret_cast<const float4*>(bl + tx * 8 + 4);
        #pragma unroll
        for (int i = 0; i < 8; ++i) {
            int gr = row0 + i * 16 + ty;
            if (gr < nNodes) {
                float4 v0 = acc[i][0], v1 = acc[i][1];
                v0.x += bb0.x; v0.y += bb0.y; v0.z += bb0.z; v0.w += bb0.w;
                v1.x += bb1.x; v1.y += bb1.y; v1.z += bb1.z; v1.w += bb1.w;
                float* p = outh + (size_t)gr * DD + tx * 8;
                *reinterpret_cast<float4*>(p)     = v0;
                *reinterpret_cast<float4*>(p + 4) = v1;
            }
        }
    }
}

// ============================ CSR build ====================================
__global__ __launch_bounds__(256) void k_zero(int* __restrict__ p, int n) {
    int i = blockIdx.x * 256 + threadIdx.x;
    if (i < n) p[i] = 0;
}

__global__ __launch_bounds__(256) void k_hist(
    const int* __restrict__ dst, int* __restrict__ deg, int nEdges) {
    int e = blockIdx.x * 256 + threadIdx.x;
    if (e < nEdges) atomicAdd(&deg[dst[e]], 1);
}

// Per-chunk (1024) exclusive scan; chunkSum[b] = chunk total.
__global__ __launch_bounds__(1024) void k_scanA(
    const int* __restrict__ deg, int* __restrict__ off,
    int* __restrict__ chunkSum, int n) {
    __shared__ int s[1024];
    const int tid = threadIdx.x;
    const int i = blockIdx.x * 1024 + tid;
    int v = (i < n) ? deg[i] : 0;
    s[tid] = v;
    __syncthreads();
    for (int o = 1; o < 1024; o <<= 1) {
        int t = (tid >= o) ? s[tid - o] : 0;
        __syncthreads();
        s[tid] += t;
        __syncthreads();
    }
    if (i < n) off[i] = s[tid] - v;            // exclusive
    if (tid == 1023) chunkSum[blockIdx.x] = s[1023];
}

// Single block: exclusive scan of chunk sums (nChunks <= 128).
__global__ __launch_bounds__(128) void k_scanB(int* __restrict__ chunkSum, int nChunks) {
    __shared__ int s[128];
    const int tid = threadIdx.x;
    int v = (tid < nChunks) ? chunkSum[tid] : 0;
    s[tid] = v;
    __syncthreads();
    for (int o = 1; o < 128; o <<= 1) {
        int t = (tid >= o) ? s[tid - o] : 0;
        __syncthreads();
        s[tid] += t;
        __syncthreads();
    }
    if (tid < nChunks) chunkSum[tid] = s[tid] - v;   // exclusive base per chunk
}

__global__ __launch_bounds__(256) void k_scanC(
    int* __restrict__ off, int* __restrict__ pos,
    const int* __restrict__ chunkBase, int n, int total) {
    int i = blockIdx.x * 256 + threadIdx.x;
    if (i < n) {
        int o = off[i] + chunkBase[i >> 10];
        off[i] = o;
        pos[i] = o;
    }
    if (i == 0) off[n] = total;
}

__global__ __launch_bounds__(256) void k_scatter(
    const int* __restrict__ src, const int* __restrict__ dst,
    const int* __restrict__ et, int* __restrict__ pos,
    int* __restrict__ csr, int nEdges) {
    int e = blockIdx.x * 256 + threadIdx.x;
    if (e < nEdges) {
        int d = dst[e];
        int j = atomicAdd(&pos[d], 1);
        csr[j] = (src[e] << 2) | et[e];        // src < 2^17, et < 4
    }
}

// ============================ Gather (atomic-free) =========================
// One 32-lane half-wave per dst node; each lane owns a float4 of the row.
// Block = 256 threads = 4 waves = 8 nodes  =>  grid = ceil(N/8).
__global__ __launch_bounds__(256) void rgcn_gather(
    const float* __restrict__ xW,     // [N,3,128]
    const int* __restrict__ off,      // [N+1]
    const int* __restrict__ csr,      // [E] packed (src<<2)|rel
    float* __restrict__ outh,         // [N,128] — already holds self+bias
    int nNodes)
{
    const int gtid = blockIdx.x * 256 + threadIdx.x;
    const int gw   = gtid >> 6;                 // global wave
    const int lane = threadIdx.x & 63;
    const int sub  = lane >> 5;                 // node within pair
    const int li   = lane & 31;                 // float4 slot (li*4 .. li*4+3)
    const int n    = gw * 2 + sub;
    if (n >= nNodes) return;

    const int b    = off[n];
    const int eend = off[n + 1];

    float4 acc = float4{0.f, 0.f, 0.f, 0.f};
    int j = b;
    // 4-way unroll: 4 independent in-flight gathers per iteration (MLP).
    for (; j + 3 < eend; j += 4) {
        int p0 = csr[j], p1 = csr[j + 1], p2 = csr[j + 2], p3 = csr[j + 3];
        const float4 v0 = *reinterpret_cast<const float4*>(
            xW + ((size_t)(p0 >> 2) * 3 + (p0 & 3)) * DD + li * 4);
        const float4 v1 = *reinterpret_cast<const float4*>(
            xW + ((size_t)(p1 >> 2) * 3 + (p1 & 3)) * DD + li * 4);
        const float4 v2 = *reinterpret_cast<const float4*>(
            xW + ((size_t)(p2 >> 2) * 3 + (p2 & 3)) * DD + li * 4);
        const float4 v3 = *reinterpret_cast<const float4*>(
            xW + ((size_t)(p3 >> 2) * 3 + (p3 & 3)) * DD + li * 4);
        acc.x += (v0.x + v1.x) + (v2.x + v3.x);
        acc.y += (v0.y + v1.y) + (v2.y + v3.y);
        acc.z += (v0.z + v1.z) + (v2.z + v3.z);
        acc.w += (v0.w + v1.w) + (v2.w + v3.w);
    }
    for (; j < eend; ++j) {
        int p0 = csr[j];
        const float4 v0 = *reinterpret_cast<const float4*>(
            xW + ((size_t)(p0 >> 2) * 3 + (p0 & 3)) * DD + li * 4);
        acc.x += v0.x; acc.y += v0.y; acc.z += v0.z; acc.w += v0.w;
    }

    float* o = outh + (size_t)n * DD + li * 4;
    float4 cur = *reinterpret_cast<const float4*>(o);
    cur.x += acc.x; cur.y += acc.y; cur.z += acc.z; cur.w += acc.w;
    *reinterpret_cast<float4*>(o) = cur;
}

// ============================ Launch =======================================
extern "C" void kernel_launch(void* const* d_in, const int* in_sizes, int n_in,
                              void* d_out, int out_size, void* d_ws, size_t ws_size,
                              hipStream_t stream) {
    const float* feat  = (const float*)d_in[0];   // [N,128]
    const float* W     = (const float*)d_in[1];   // [3,3,128,128]
    const float* Wself = (const float*)d_in[2];   // [3,128,128]
    const float* bias  = (const float*)d_in[3];   // [3,128]
    const int*   src   = (const int*)d_in[4];
    const int*   dst   = (const int*)d_in[5];
    const int*   et    = (const int*)d_in[6];
    float* out = (float*)d_out;

    const int nNodes = in_sizes[0] / DD;
    const int nEdges = in_sizes[4];

    // ---- workspace layout ----
    float* xW = (float*)d_ws;                                  // N*3*128 f32
    float* h1 = xW + (size_t)nNodes * 3 * DD;                  // N*128 f32
    float* h2 = h1 + (size_t)nNodes * DD;                      // N*128 f32
    int* ip   = (int*)(h2 + (size_t)nNodes * DD);
    int* deg      = ip;                                        // N
    int* off      = deg + nNodes;                              // N+1
    int* pos      = off + nNodes + 1;                          // N
    int* chunkSum = pos + nNodes;                              // padded 1024
    int* csr      = chunkSum + 1024;                           // E

    const int nChunks = (nNodes + 1023) / 1024;
    const int nEB = (nEdges + 255) / 256;
    const int nNB = (nNodes + 255) / 256;

    // ---- CSR build (once, reused 3x) ----
    k_zero   <<<nNB, 256, 0, stream>>>(deg, nNodes);
    k_hist   <<<nEB, 256, 0, stream>>>(dst, deg, nEdges);
    k_scanA  <<<nChunks, 1024, 0, stream>>>(deg, off, chunkSum, nNodes);
    k_scanB  <<<1, 128, 0, stream>>>(chunkSum, nChunks);
    k_scanC  <<<nNB, 256, 0, stream>>>(off, pos, chunkSum, nNodes, nEdges);
    k_scatter<<<nEB, 256, 0, stream>>>(src, dst, et, pos, csr, nEdges);

    // ---- 3 layers ----
    dim3 gridX((nNodes + 127) / 128, 4);
    const int gatherBlocks = (nNodes + 7) / 8;   // 8 nodes per 256-thread block

    const float* hin = feat;
    float* houts[3] = {h1, h2, out};

    for (int l = 0; l < 3; ++l) {
        rgcn_xform<<<gridX, 256, 0, stream>>>(
            hin,
            W     + (size_t)l * 3 * DD * DD,
            Wself + (size_t)l * DD * DD,
            bias  + (size_t)l * DD,
            xW, houts[l], nNodes);
        rgcn_gather<<<gatherBlocks, 256, 0, stream>>>(
            xW, off, csr, houts[l], nNodes);
        hin = houts[l];
    }
}

// Round 5
// 913.373 us; speedup vs baseline: 1.2898x; 1.2898x over previous
//
#include <hip/hip_runtime.h>

// RGCN 3-layer forward, MI355X — aggregate-first + bf16x4 split-precision MFMA.
//
// Per layer l:
//   aggF[d,r,:] = sum_{e: dst=d, et=r} h[src[e], :]                (gather, CSR by (dst,rel))
//   h' = [h | aggF0 | aggF1 | aggF2] @ [Wsl; W0; W1; W2] + bias    (K=512 MFMA GEMM)
// h stored as bf16 hi+lo pairs (split precision); GEMM does 4 MFMAs per product
// (hi*hi + hi*lo + lo*hi + lo*lo) accumulating fp32 — ~2^-17 relative error.

#define DD 128
#define KF 512                      // fused K = 128 (self) + 3*128 (relations)

typedef __attribute__((ext_vector_type(8))) short short8;   // 8 bf16 = 4 VGPRs
typedef __attribute__((ext_vector_type(4))) float f32x4;

__device__ __forceinline__ float bf2f(ushort u) {
    return __uint_as_float(((unsigned)u) << 16);
}
__device__ __forceinline__ ushort f2bf(float f) {            // round-to-nearest-even
    unsigned b = __float_as_uint(f);
    return (ushort)((b + 0x7FFFu + ((b >> 16) & 1u)) >> 16);
}
__device__ __forceinline__ void splitbf(float f, ushort& hi, ushort& lo) {
    hi = f2bf(f);
    lo = f2bf(f - bf2f(hi));
}

#define GLOAD_LDS16(g, l)                                                      \
    __builtin_amdgcn_global_load_lds(                                          \
        (const __attribute__((address_space(1))) void*)(g),                    \
        (__attribute__((address_space(3))) void*)(l), 16, 0, 0)

// ===================== prep: split features into bf16 hi/lo =================
__global__ __launch_bounds__(256) void k_split_feat(
    const float* __restrict__ feat, ushort* __restrict__ h_hi,
    ushort* __restrict__ h_lo, int n4)
{
    int i = blockIdx.x * 256 + threadIdx.x;
    if (i >= n4) return;
    float4 v = reinterpret_cast<const float4*>(feat)[i];
    ushort4 hh, ll;
    splitbf(v.x, hh.x, ll.x); splitbf(v.y, hh.y, ll.y);
    splitbf(v.z, hh.z, ll.z); splitbf(v.w, hh.w, ll.w);
    reinterpret_cast<ushort4*>(h_hi)[i] = hh;
    reinterpret_cast<ushort4*>(h_lo)[i] = ll;
}

// ===================== prep: weights -> MFMA-fragment-linear image ==========
// bimg[l][chunk c][group g][lane v][j] = B[k = c*32 + (v>>4)*8 + j][col = g*16 + (v&15)]
// where B rows 0-127 = Wself[l], rows 128-511 = W[l] (r-major, i-major).
__global__ __launch_bounds__(256) void k_build_bimg(
    const float* __restrict__ W, const float* __restrict__ Wself,
    ushort* __restrict__ bh, ushort* __restrict__ bl_)
{
    int idx = blockIdx.x * 256 + threadIdx.x;
    if (idx >= 3 * 65536) return;
    int l = idx >> 16, rem = idx & 65535;
    int j = rem & 7, v = (rem >> 3) & 63, g = (rem >> 9) & 7, c = (rem >> 12) & 15;
    int col = g * 16 + (v & 15);
    int k = c * 32 + ((v >> 4) * 8) + j;
    float val;
    if (k < 128) val = Wself[((size_t)l * 128 + k) * 128 + col];
    else {
        int kk = k - 128, r = kk >> 7, i = kk & 127;
        val = W[(((size_t)l * 3 + r) * 128 + i) * 128 + col];
    }
    ushort hi, lo; splitbf(val, hi, lo);
    bh[idx] = hi; bl_[idx] = lo;
}

// ===================== CSR build over 3N bins (bin = dst*3 + et) ============
__global__ __launch_bounds__(256) void k_zero(int* __restrict__ p, int n) {
    int i = blockIdx.x * 256 + threadIdx.x;
    if (i < n) p[i] = 0;
}
__global__ __launch_bounds__(256) void k_hist3(
    const int* __restrict__ dst, const int* __restrict__ et,
    int* __restrict__ deg, int nEdges) {
    int e = blockIdx.x * 256 + threadIdx.x;
    if (e < nEdges) atomicAdd(&deg[dst[e] * 3 + et[e]], 1);
}
__global__ __launch_bounds__(1024) void k_scanA(
    const int* __restrict__ deg, int* __restrict__ off,
    int* __restrict__ chunkSum, int n) {
    __shared__ int s[1024];
    const int tid = threadIdx.x;
    const int i = blockIdx.x * 1024 + tid;
    int v = (i < n) ? deg[i] : 0;
    s[tid] = v;
    __syncthreads();
    for (int o = 1; o < 1024; o <<= 1) {
        int t = (tid >= o) ? s[tid - o] : 0;
        __syncthreads();
        s[tid] += t;
        __syncthreads();
    }
    if (i < n) off[i] = s[tid] - v;
    if (tid == 1023) chunkSum[blockIdx.x] = s[1023];
}
__global__ __launch_bounds__(512) void k_scanB(int* __restrict__ chunkSum, int nChunks) {
    __shared__ int s[512];
    const int tid = threadIdx.x;
    int v = (tid < nChunks) ? chunkSum[tid] : 0;
    s[tid] = v;
    __syncthreads();
    for (int o = 1; o < 512; o <<= 1) {
        int t = (tid >= o) ? s[tid - o] : 0;
        __syncthreads();
        s[tid] += t;
        __syncthreads();
    }
    if (tid < nChunks) chunkSum[tid] = s[tid] - v;
}
__global__ __launch_bounds__(256) void k_scanC(
    int* __restrict__ off, int* __restrict__ pos,
    const int* __restrict__ chunkBase, int n, int total) {
    int i = blockIdx.x * 256 + threadIdx.x;
    if (i < n) {
        int o = off[i] + chunkBase[i >> 10];
        off[i] = o;
        pos[i] = o;
    }
    if (i == 0) off[n] = total;
}
__global__ __launch_bounds__(256) void k_scatter3(
    const int* __restrict__ src, const int* __restrict__ dst,
    const int* __restrict__ et, int* __restrict__ pos,
    int* __restrict__ csr, int nEdges) {
    int e = blockIdx.x * 256 + threadIdx.x;
    if (e < nEdges) {
        int j = atomicAdd(&pos[dst[e] * 3 + et[e]], 1);
        csr[j] = src[e];
    }
}

// ===================== gather: aggF[n,r,:] = sum h[src] (bf16 hi/lo) ========
// One 32-lane half-wave per dst node; lane owns elements li*4..li*4+3.
__global__ __launch_bounds__(256) void rgcn_gather(
    const ushort* __restrict__ h_hi, const ushort* __restrict__ h_lo,
    const int* __restrict__ off3, const int* __restrict__ csr,
    ushort* __restrict__ aggF_hi, ushort* __restrict__ aggF_lo,
    int nNodes)
{
    const int gtid = blockIdx.x * 256 + threadIdx.x;
    const int gw   = gtid >> 6;
    const int lane = threadIdx.x & 63;
    const int sub  = lane >> 5;
    const int li   = lane & 31;
    const int n    = gw * 2 + sub;
    if (n >= nNodes) return;
    const int e0 = li * 4;

    #pragma unroll
    for (int r = 0; r < 3; ++r) {
        const int b = off3[n * 3 + r];
        const int e = off3[n * 3 + r + 1];
        float ax = 0.f, ay = 0.f, az = 0.f, aw = 0.f;
        int j = b;
        for (; j + 1 < e; j += 2) {
            int s0 = csr[j], s1 = csr[j + 1];
            ushort4 h0 = *reinterpret_cast<const ushort4*>(h_hi + (size_t)s0 * DD + e0);
            ushort4 l0 = *reinterpret_cast<const ushort4*>(h_lo + (size_t)s0 * DD + e0);
            ushort4 h1 = *reinterpret_cast<const ushort4*>(h_hi + (size_t)s1 * DD + e0);
            ushort4 l1 = *reinterpret_cast<const ushort4*>(h_lo + (size_t)s1 * DD + e0);
            ax += (bf2f(h0.x) + bf2f(l0.x)) + (bf2f(h1.x) + bf2f(l1.x));
            ay += (bf2f(h0.y) + bf2f(l0.y)) + (bf2f(h1.y) + bf2f(l1.y));
            az += (bf2f(h0.z) + bf2f(l0.z)) + (bf2f(h1.z) + bf2f(l1.z));
            aw += (bf2f(h0.w) + bf2f(l0.w)) + (bf2f(h1.w) + bf2f(l1.w));
        }
        if (j < e) {
            int s0 = csr[j];
            ushort4 h0 = *reinterpret_cast<const ushort4*>(h_hi + (size_t)s0 * DD + e0);
            ushort4 l0 = *reinterpret_cast<const ushort4*>(h_lo + (size_t)s0 * DD + e0);
            ax += bf2f(h0.x) + bf2f(l0.x);
            ay += bf2f(h0.y) + bf2f(l0.y);
            az += bf2f(h0.z) + bf2f(l0.z);
            aw += bf2f(h0.w) + bf2f(l0.w);
        }
        const size_t o = ((size_t)n * 3 + r) * DD + e0;
        ushort4 hh, ll;
        splitbf(ax, hh.x, ll.x); splitbf(ay, hh.y, ll.y);
        splitbf(az, hh.z, ll.z); splitbf(aw, hh.w, ll.w);
        *reinterpret_cast<ushort4*>(aggF_hi + o) = hh;
        *reinterpret_cast<ushort4*>(aggF_lo + o) = ll;
    }
}

// ===================== MFMA GEMM: [h|aggF] @ Bfused + bias ==================
// 128x128 tile per block, 4 waves (2x2), each wave 64x64 = 4x4 frags of 16x16.
// LDS fragment-linear: tile t, lane l -> 8 consecutive bf16 at (t*64+l)*16 B.
// A frag: row = l&15 (of 16-row tile), k = (l>>4)*8+j ; B frag: col = l&15.
__global__ __launch_bounds__(256) void rgcn_mfma(
    const ushort* __restrict__ h_hi, const ushort* __restrict__ h_lo,     // [N,128]
    const ushort* __restrict__ aggF_hi, const ushort* __restrict__ aggF_lo, // [N,384]
    const ushort* __restrict__ bimg_hi, const ushort* __restrict__ bimg_lo, // layer's 65536
    const float* __restrict__ bl,                                         // [128]
    ushort* __restrict__ out_hi, ushort* __restrict__ out_lo,             // layers 0,1
    float* __restrict__ out_f32,                                          // layer 2
    int isFinal, int nNodes)
{
    __shared__ ushort smem[16384];          // 32 KB: Ah | Al | Bh | Bl (4096 each)
    ushort* Ah = smem;
    ushort* Al = smem + 4096;
    ushort* Bh = smem + 8192;
    ushort* Bl = smem + 12288;

    const int t = threadIdx.x;
    const int w = t >> 6;                   // wave 0..3
    const int lane = t & 63;
    const int wr = w >> 1, wc = w & 1;      // wave's 64x64 quadrant
    const int row0 = blockIdx.x * 128;

    f32x4 acc[4][4];
    #pragma unroll
    for (int i = 0; i < 4; ++i)
        #pragma unroll
        for (int jn = 0; jn < 4; ++jn) acc[i][jn] = f32x4{0.f, 0.f, 0.f, 0.f};

    // staging: wave w stages A tiles mt=2w,2w+1 and B groups g=2w,2w+1
    const int arow0 = row0 + (2 * w) * 16 + (lane & 15);
    const int arow1 = row0 + (2 * w + 1) * 16 + (lane & 15);
    const int asub  = (lane >> 4) * 8;

    for (int ch = 0; ch < 16; ++ch) {
        const int kc = ch * 32;
        __syncthreads();                    // prev compute done before overwrite
        // ---- stage A hi/lo ----
        const ushort* sH; const ushort* sL; size_t stride; int kloc;
        if (kc < 128) { sH = h_hi; sL = h_lo; stride = DD;     kloc = kc; }
        else          { sH = aggF_hi; sL = aggF_lo; stride = 384; kloc = kc - 128; }
        GLOAD_LDS16(sH + (size_t)arow0 * stride + kloc + asub, Ah + (2 * w) * 512);
        GLOAD_LDS16(sH + (size_t)arow1 * stride + kloc + asub, Ah + (2 * w + 1) * 512);
        GLOAD_LDS16(sL + (size_t)arow0 * stride + kloc + asub, Al + (2 * w) * 512);
        GLOAD_LDS16(sL + (size_t)arow1 * stride + kloc + asub, Al + (2 * w + 1) * 512);
        // ---- stage B hi/lo (fragment-linear in global already) ----
        {
            const size_t bbase0 = ((size_t)(ch * 8 + 2 * w) * 64 + lane) * 8;
            const size_t bbase1 = ((size_t)(ch * 8 + 2 * w + 1) * 64 + lane) * 8;
            GLOAD_LDS16(bimg_hi + bbase0, Bh + (2 * w) * 512);
            GLOAD_LDS16(bimg_hi + bbase1, Bh + (2 * w + 1) * 512);
            GLOAD_LDS16(bimg_lo + bbase0, Bl + (2 * w) * 512);
            GLOAD_LDS16(bimg_lo + bbase1, Bl + (2 * w + 1) * 512);
        }
        __syncthreads();                    // vmcnt(0)+barrier (compiler-inserted)

        // ---- fragments ----
        short8 ah[4], al[4], bh[4], blo[4];
        #pragma unroll
        for (int i = 0; i < 4; ++i) {
            const int mt = wr * 4 + i;
            ah[i]  = *reinterpret_cast<const short8*>(Ah + mt * 512 + lane * 8);
            al[i]  = *reinterpret_cast<const short8*>(Al + mt * 512 + lane * 8);
            const int g = wc * 4 + i;
            bh[i]  = *reinterpret_cast<const short8*>(Bh + g * 512 + lane * 8);
            blo[i] = *reinterpret_cast<const short8*>(Bl + g * 512 + lane * 8);
        }
        // ---- 4x4 frags x 4 MFMAs (hi*hi + hi*lo + lo*hi + lo*lo) ----
        #pragma unroll
        for (int i = 0; i < 4; ++i)
            #pragma unroll
            for (int jn = 0; jn < 4; ++jn) {
                acc[i][jn] = __builtin_amdgcn_mfma_f32_16x16x32_bf16(ah[i], bh[jn],  acc[i][jn], 0, 0, 0);
                acc[i][jn] = __builtin_amdgcn_mfma_f32_16x16x32_bf16(ah[i], blo[jn], acc[i][jn], 0, 0, 0);
                acc[i][jn] = __builtin_amdgcn_mfma_f32_16x16x32_bf16(al[i], bh[jn],  acc[i][jn], 0, 0, 0);
                acc[i][jn] = __builtin_amdgcn_mfma_f32_16x16x32_bf16(al[i], blo[jn], acc[i][jn], 0, 0, 0);
            }
    }

    // ---- epilogue: C/D layout col=lane&15, row=(lane>>4)*4+reg ----
    const int colb = wc * 64 + (lane & 15);
    const int rowb = row0 + wr * 64 + (lane >> 4) * 4;
    #pragma unroll
    for (int i = 0; i < 4; ++i) {
        #pragma unroll
        for (int jn = 0; jn < 4; ++jn) {
            const int col = colb + jn * 16;
            const float bb = bl[col];
            #pragma unroll
            for (int rr = 0; rr < 4; ++rr) {
                const int row = rowb + i * 16 + rr;
                if (row < nNodes) {
                    const float v = acc[i][jn][rr] + bb;
                    if (isFinal) {
                        out_f32[(size_t)row * DD + col] = v;
                    } else {
                        ushort hi, lo; splitbf(v, hi, lo);
                        out_hi[(size_t)row * DD + col] = hi;
                        out_lo[(size_t)row * DD + col] = lo;
                    }
                }
            }
        }
    }
}

// ============================ Launch =======================================
extern "C" void kernel_launch(void* const* d_in, const int* in_sizes, int n_in,
                              void* d_out, int out_size, void* d_ws, size_t ws_size,
                              hipStream_t stream) {
    const float* feat  = (const float*)d_in[0];   // [N,128]
    const float* W     = (const float*)d_in[1];   // [3,3,128,128]
    const float* Wself = (const float*)d_in[2];   // [3,128,128]
    const float* bias  = (const float*)d_in[3];   // [3,128]
    const int*   src   = (const int*)d_in[4];
    const int*   dst   = (const int*)d_in[5];
    const int*   et    = (const int*)d_in[6];
    float* out = (float*)d_out;

    const int nNodes = in_sizes[0] / DD;
    const int nEdges = in_sizes[4];
    const int nBins  = nNodes * 3;

    // ---- workspace layout (ushort-first, ints after) ----
    ushort* h_hi    = (ushort*)d_ws;                       // N*128
    ushort* h_lo    = h_hi + (size_t)nNodes * DD;          // N*128
    ushort* aggF_hi = h_lo + (size_t)nNodes * DD;          // N*384
    ushort* aggF_lo = aggF_hi + (size_t)nNodes * 384;      // N*384
    ushort* bimg_hi = aggF_lo + (size_t)nNodes * 384;      // 3*65536
    ushort* bimg_lo = bimg_hi + 3 * 65536;                 // 3*65536
    int* ip = (int*)(bimg_lo + 3 * 65536);
    int* deg3     = ip;                                    // 3N
    int* off3     = deg3 + nBins;                          // 3N+1
    int* pos3     = off3 + nBins + 1;                      // 3N
    int* chunkSum = pos3 + nBins;                          // 512
    int* csr      = chunkSum + 512;                        // E

    const int nChunks = (nBins + 1023) / 1024;
    const int nEB = (nEdges + 255) / 256;
    const int nBB = (nBins + 255) / 256;

    // ---- prep ----
    const int n4 = nNodes * DD / 4;
    k_split_feat<<<(n4 + 255) / 256, 256, 0, stream>>>(feat, h_hi, h_lo, n4);
    k_build_bimg<<<(3 * 65536 + 255) / 256, 256, 0, stream>>>(W, Wself, bimg_hi, bimg_lo);

    // ---- CSR build over (dst,rel) bins ----
    k_zero    <<<nBB, 256, 0, stream>>>(deg3, nBins);
    k_hist3   <<<nEB, 256, 0, stream>>>(dst, et, deg3, nEdges);
    k_scanA   <<<nChunks, 1024, 0, stream>>>(deg3, off3, chunkSum, nBins);
    k_scanB   <<<1, 512, 0, stream>>>(chunkSum, nChunks);
    k_scanC   <<<nBB, 256, 0, stream>>>(off3, pos3, chunkSum, nBins, nEdges);
    k_scatter3<<<nEB, 256, 0, stream>>>(src, dst, et, pos3, csr, nEdges);

    // ---- 3 layers: gather then GEMM (in-place h update; final -> d_out) ----
    const int gatherBlocks = (nNodes + 7) / 8;     // 8 nodes / 256-thread block
    const int gemmBlocks   = (nNodes + 127) / 128;

    for (int l = 0; l < 3; ++l) {
        rgcn_gather<<<gatherBlocks, 256, 0, stream>>>(
            h_hi, h_lo, off3, csr, aggF_hi, aggF_lo, nNodes);
        rgcn_mfma<<<gemmBlocks, 256, 0, stream>>>(
            h_hi, h_lo, aggF_hi, aggF_lo,
            bimg_hi + l * 65536, bimg_lo + l * 65536,
            bias + (size_t)l * DD,
            h_hi, h_lo, out, (l == 2) ? 1 : 0, nNodes);
    }
}